// Round 7
// baseline (298.437 us; speedup 1.0000x reference)
//
#include <hip/hip_runtime.h>

#define NH 8
#define HD 32
#define NL 4
#define NP 4
#define DM 256
#define LEN_IN_C 13294
#define LQ_C 13294
#define B_C 2
#define M_TOTAL (B_C * LQ_C)           // 26588
#define MT_TILES 1662                  // ceil(26588/16)
#define MT_PAD 1664                    // padded to multiple of 4 row-tiles
#define RBLK (MT_PAD / 4)              // 416 row-blocks of 64 rows

typedef __attribute__((ext_vector_type(8))) short short8;
typedef __attribute__((ext_vector_type(4))) float floatx4;

__device__ __forceinline__ unsigned short f2bf(float x) {
    union { float f; unsigned int u; } a; a.f = x;
    unsigned int r = (a.u + 0x7FFFu + ((a.u >> 16) & 1u)) >> 16;
    return (unsigned short)r;
}
__device__ __forceinline__ float bflo(unsigned int u) {
    union { unsigned int u; float f; } a; a.u = u << 16; return a.f;
}
__device__ __forceinline__ float bfhi(unsigned int u) {
    union { unsigned int u; float f; } a; a.u = u & 0xffff0000u; return a.f;
}

// async global->LDS, 16 B per lane: LDS dest = uniform base + lane*16
__device__ __forceinline__ void glds16(const void* g, void* l) {
    __builtin_amdgcn_global_load_lds(
        (const __attribute__((address_space(1))) unsigned int*)g,
        (__attribute__((address_space(3))) unsigned int*)l, 16, 0, 0);
}

// ---------------------------------------------------------------------------
// conv_all: A-activation conversion (both matrices) + all weight conversions
// + bias fuse in ONE launch.
// A: [M,256] fp32 -> swizzled bf16 fragments, padded to MT_PAD row-tiles.
//   Unit u = (rt*8+kc)*64+lane; lane = m+16*q holds A[rt*16+m][kc*32+q*8..+8].
// ---------------------------------------------------------------------------
__device__ __forceinline__ void conv_b_body(const float* __restrict__ W,
                                            unsigned short* __restrict__ Bsw,
                                            int Nsrc, int NTsrc, int NTtotal, int ntOff,
                                            int vblk) {
    const int u = vblk * 256 + threadIdx.x;
    const int lane = u & 63;
    const int unit = u >> 6;
    const int ntl = unit % NTsrc;
    const int kc = unit / NTsrc;
    const int n = ntl * 16 + (lane & 15);
    const int k0 = kc * 32 + (lane >> 4) * 8;
    short8 v;
#pragma unroll
    for (int j = 0; j < 8; ++j)
        v[j] = (short)f2bf(W[(size_t)(k0 + j) * Nsrc + n]);
    ((short8*)Bsw)[(size_t)(kc * NTtotal + ntOff + ntl) * 64 + lane] = v;
}

__global__ __launch_bounds__(256) void conv_all_kernel(const float* __restrict__ A0,
                                                       unsigned short* __restrict__ D0,
                                                       const float* __restrict__ A1,
                                                       unsigned short* __restrict__ D1,
                                                       const float* __restrict__ Wv,
                                                       const float* __restrict__ Woff,
                                                       const float* __restrict__ Wattn,
                                                       const float* __restrict__ Wout,
                                                       const float* __restrict__ boff,
                                                       const float* __restrict__ battn,
                                                       unsigned short* __restrict__ BswV,
                                                       unsigned short* __restrict__ BswOA,
                                                       unsigned short* __restrict__ BswO,
                                                       float* __restrict__ fbias,
                                                       int M) {
    const int bx = blockIdx.x;
    if (bx < MT_PAD * 2) {
        const float* A = blockIdx.y ? A1 : A0;
        unsigned short* Asw = blockIdx.y ? D1 : D0;
        const int u = bx * 256 + threadIdx.x;
        const int lane = u & 63;
        const int kc = (u >> 6) & 7;
        const int rt = u >> 9;
        const int row = rt * 16 + (lane & 15);
        const int col0 = kc * 32 + (lane >> 4) * 8;
        unsigned short tmp[8];
        if (row < M) {
            const float4 f0 = *(const float4*)(A + (size_t)row * 256 + col0);
            const float4 f1 = *(const float4*)(A + (size_t)row * 256 + col0 + 4);
            tmp[0] = f2bf(f0.x); tmp[1] = f2bf(f0.y); tmp[2] = f2bf(f0.z); tmp[3] = f2bf(f0.w);
            tmp[4] = f2bf(f1.x); tmp[5] = f2bf(f1.y); tmp[6] = f2bf(f1.z); tmp[7] = f2bf(f1.w);
        } else {
#pragma unroll
            for (int j = 0; j < 8; ++j) tmp[j] = 0;
        }
        short8 v;
#pragma unroll
        for (int j = 0; j < 8; ++j) v[j] = (short)tmp[j];
        ((short8*)Asw)[u] = v;
    } else {
        const int wblk = (bx - MT_PAD * 2) + 57 * blockIdx.y;   // 0..113
        if (wblk < 32)       conv_b_body(Wv,    BswV,  256, 16, 16, 0,  wblk);
        else if (wblk < 64)  conv_b_body(Woff,  BswOA, 256, 16, 24, 0,  wblk - 32);
        else if (wblk < 80)  conv_b_body(Wattn, BswOA, 128,  8, 24, 16, wblk - 64);
        else if (wblk < 112) conv_b_body(Wout,  BswO,  256, 16, 16, 0,  wblk - 80);
        else {
            const int t = threadIdx.x;
            if (t < 384) fbias[t] = (t < 256) ? boff[t] : battn[t - 256];
        }
    }
}

// ---------------------------------------------------------------------------
// Barrier-free 64x64 GEMM block, full K=256 staged in LDS up front.
//   As: 32 units (4 rt x 8 kc), Bs: 32 units (8 kc x 4 nt) -> 64 KB total.
//   64 async global_load_lds, ONE __syncthreads, then pure ds_read+MFMA.
// Wave w owns n-tile w (16 cols) x all 4 row-tiles.
// VAL_LAYOUT: store bf16 head-major value[h][M][32]; else fp32 row-major.
// ---------------------------------------------------------------------------
template <bool VAL_LAYOUT, int NT_B, int NCOLS>
__device__ __forceinline__ void gemm64_body(short8* As, short8* Bs,
                                            const short8* __restrict__ Au,
                                            const short8* __restrict__ Bu,
                                            int rtile0, int ntB,
                                            const float* __restrict__ bias,
                                            void* __restrict__ Cout, int M) {
    const int tid = threadIdx.x;
    const int lane = tid & 63;
    const int wave = tid >> 6;

#pragma unroll
    for (int i = 0; i < 16; ++i) {
        const int u = wave * 16 + i;
        if (u < 32) {
            // A unit: rt = u>>3, kc = u&7
            glds16(&Au[(size_t)((rtile0 + (u >> 3)) * 8 + (u & 7)) * 64 + lane], &As[u * 64]);
        } else {
            const int v = u - 32;     // B unit: kc = v>>2, ntl = v&3
            glds16(&Bu[(size_t)((v >> 2) * NT_B + ntB + (v & 3)) * 64 + lane], &Bs[v * 64]);
        }
    }
    __syncthreads();

    floatx4 acc[4];
#pragma unroll
    for (int r = 0; r < 4; ++r) acc[r] = (floatx4){0.f, 0.f, 0.f, 0.f};

#pragma unroll
    for (int kc = 0; kc < 8; ++kc) {
        const short8 b  = Bs[(kc * 4 + wave) * 64 + lane];
        const short8 a0 = As[(0 * 8 + kc) * 64 + lane];
        const short8 a1 = As[(1 * 8 + kc) * 64 + lane];
        const short8 a2 = As[(2 * 8 + kc) * 64 + lane];
        const short8 a3 = As[(3 * 8 + kc) * 64 + lane];
        acc[0] = __builtin_amdgcn_mfma_f32_16x16x32_bf16(a0, b, acc[0], 0, 0, 0);
        acc[1] = __builtin_amdgcn_mfma_f32_16x16x32_bf16(a1, b, acc[1], 0, 0, 0);
        acc[2] = __builtin_amdgcn_mfma_f32_16x16x32_bf16(a2, b, acc[2], 0, 0, 0);
        acc[3] = __builtin_amdgcn_mfma_f32_16x16x32_bf16(a3, b, acc[3], 0, 0, 0);
    }

    const int colq = lane & 15;
    const int rowq = (lane >> 4) * 4;
    const int col = (ntB + wave) * 16 + colq;
    const float bc = bias[col];
#pragma unroll
    for (int r = 0; r < 4; ++r) {
#pragma unroll
        for (int reg = 0; reg < 4; ++reg) {
            const int row = (rtile0 + r) * 16 + rowq + reg;
            if (row < M) {
                const float v = acc[r][reg] + bc;
                if (VAL_LAYOUT)
                    ((unsigned short*)Cout)[((size_t)(col >> 5) * M + row) * 32 + (col & 31)] = f2bf(v);
                else
                    ((float*)Cout)[(size_t)row * NCOLS + col] = v;
            }
        }
    }
}

// dual: grid(10, RBLK). x<4: value colblocks (head-major bf16 out);
// x>=4: fused colblocks (fp32, 384 cols). Same-row blocks adjacent in x for
// A L2-temporal reuse.
__global__ __launch_bounds__(256, 2) void dual_gemm_kernel(const short8* __restrict__ AuV,
                                                           const short8* __restrict__ AuQ,
                                                           const short8* __restrict__ BuV,
                                                           const short8* __restrict__ BuOA,
                                                           const float* __restrict__ bv,
                                                           const float* __restrict__ fbias,
                                                           unsigned short* __restrict__ value,
                                                           float* __restrict__ fused, int M) {
    __shared__ short8 As[32 * 64];   // 32 KB
    __shared__ short8 Bs[32 * 64];   // 32 KB
    const int rtile0 = blockIdx.y * 4;
    const int x = blockIdx.x;
    if (x < 4)
        gemm64_body<true, 16, 256>(As, Bs, AuV, BuV, rtile0, x * 4, bv, value, M);
    else
        gemm64_body<false, 24, 384>(As, Bs, AuQ, BuOA, rtile0, (x - 4) * 4, fbias, fused, M);
}

__global__ __launch_bounds__(256, 2) void out_gemm_kernel(const short8* __restrict__ AuAcc,
                                                          const short8* __restrict__ BuO,
                                                          const float* __restrict__ bout,
                                                          float* __restrict__ out, int M) {
    __shared__ short8 As[32 * 64];
    __shared__ short8 Bs[32 * 64];
    gemm64_body<false, 16, 256>(As, Bs, AuAcc, BuO, blockIdx.y * 4, blockIdx.x * 4,
                                bout, out, M);
}

// ---------------------------------------------------------------------------
// Sampler v4: value is head-major [h][M][32] bf16 -> the two x-corners of a
// row are CONTIGUOUS 128 B. Lanes 0-3 of each 8-lane group take column x0,
// lanes 4-7 take x1 (one uint4 = 8 dims per lane per row); shfl_xor(4)
// merges the halves at the end. 32 VMEM instrs/thread (was 64).
// ---------------------------------------------------------------------------
__global__ __launch_bounds__(256, 4) void msda_sample_kernel(const float* __restrict__ refp,
                                                             const unsigned short* __restrict__ value,
                                                             const float* __restrict__ fused,
                                                             unsigned short* __restrict__ AccSw) {
    constexpr int lvl_hw[4] = {100, 50, 25, 13};
    constexpr int lvl_s[4] = {0, 10000, 12500, 13125};

    const int bq0 = blockIdx.x * 4;
    const int tid = threadIdx.x;

    __shared__ float s_ref[32];
    __shared__ int2 s_pi[4 * 8 * 17];     // row0/row1 byte offsets (col pair base)
    __shared__ float4 s_pw[4 * 8 * 17];   // premult weights: r0c0, r0c1, r1c0, r1c1

    if (tid < 32) s_ref[tid] = refp[(size_t)bq0 * 8 + tid];
    __syncthreads();

#pragma unroll
    for (int jj = 0; jj < 2; ++jj) {
        const int job = jj * 256 + tid;
        const int qq = job >> 7;
        const int t = job & 127;
        const int h = t >> 4;
        const int l = (t >> 2) & 3;
        const int bq = bq0 + qq;
        const int b = (bq >= LQ_C) ? 1 : 0;

        const float logit = fused[(size_t)bq * 384 + 256 + t];
        float mx = logit;
#pragma unroll
        for (int mask = 1; mask < 16; mask <<= 1) mx = fmaxf(mx, __shfl_xor(mx, mask));
        const float e = expf(logit - mx);
        float s = e;
#pragma unroll
        for (int mask = 1; mask < 16; mask <<= 1) s += __shfl_xor(s, mask);
        const float aw = e / s;

        const int whl = lvl_hw[l];
        const float fwh = (float)whl;
        const float2 oxy = *(const float2*)(fused + (size_t)bq * 384 + t * 2);
        const float x = s_ref[qq * 8 + l * 2] * fwh + oxy.x - 0.5f;
        const float y = s_ref[qq * 8 + l * 2 + 1] * fwh + oxy.y - 0.5f;
        const float x0f = floorf(x), y0f = floorf(y);
        const float tx = x - x0f, ty = y - y0f;
        const int ix0 = (int)x0f, iy0 = (int)y0f;

        const bool yv0 = (unsigned)iy0 < (unsigned)whl;
        const bool yv1 = (unsigned)(iy0 + 1) < (unsigned)whl;
        const int cy0 = min(max(iy0, 0), whl - 1);
        const int cy1 = min(max(iy0 + 1, 0), whl - 1);

        // column pair base bx in [0, w-2]; both bx, bx+1 valid.
        const int bxc = min(max(ix0, 0), whl - 2);
        const float wx0 = 1.f - tx, wx1 = tx;
        // weight landing on column bxc / bxc+1 (0 if that corner is OOB)
        const float c0w = (ix0 == bxc) ? wx0 : ((ix0 + 1 == bxc) ? wx1 : 0.f);
        const float c1w = (ix0 == bxc) ? wx1 : ((ix0 == bxc + 1) ? wx0 : 0.f);

        const int base = (h * M_TOTAL + b * LEN_IN_C + lvl_s[l]) * 32;
        int2 off;
        off.x = (base + (cy0 * whl + bxc) * 32) * 2;   // byte offset, row y0
        off.y = (base + (cy1 * whl + bxc) * 32) * 2;   // byte offset, row y1
        const float a0 = aw * (1.f - ty) * (yv0 ? 1.f : 0.f);
        const float a1 = aw * ty * (yv1 ? 1.f : 0.f);
        float4 wv;
        wv.x = a0 * c0w;   // row0 col0
        wv.y = a0 * c1w;   // row0 col1
        wv.z = a1 * c0w;   // row1 col0
        wv.w = a1 * c1w;   // row1 col1
        const int slot = (qq * 8 + h) * 17 + (t & 15);
        s_pi[slot] = off;
        s_pw[slot] = wv;
    }
    __syncthreads();

    const int qq = tid >> 6;
    const int h = (tid >> 3) & 7;
    const int l8 = tid & 7;
    const int half = l8 >> 2;                    // 0: col x0, 1: col x1
    const char* vbp = (const char*)value + l8 * 16;
    const int pbase = (qq * 8 + h) * 17;

    float acc[8] = {0.f, 0.f, 0.f, 0.f, 0.f, 0.f, 0.f, 0.f};
#pragma unroll
    for (int g = 0; g < 4; ++g) {
        int2 off[4]; float4 ww[4]; uint4 r0[4], r1[4];
#pragma unroll
        for (int p = 0; p < 4; ++p) {
            off[p] = s_pi[pbase + g * 4 + p];
            ww[p] = s_pw[pbase + g * 4 + p];
        }
#pragma unroll
        for (int p = 0; p < 4; ++p) {
            r0[p] = *(const uint4*)(vbp + off[p].x);
            r1[p] = *(const uint4*)(vbp + off[p].y);
        }
#pragma unroll
        for (int p = 0; p < 4; ++p) {
            const float w0 = half ? ww[p].y : ww[p].x;
            const float w1 = half ? ww[p].w : ww[p].z;
            acc[0] += w0 * bflo(r0[p].x); acc[1] += w0 * bfhi(r0[p].x);
            acc[2] += w0 * bflo(r0[p].y); acc[3] += w0 * bfhi(r0[p].y);
            acc[4] += w0 * bflo(r0[p].z); acc[5] += w0 * bfhi(r0[p].z);
            acc[6] += w0 * bflo(r0[p].w); acc[7] += w0 * bfhi(r0[p].w);
            acc[0] += w1 * bflo(r1[p].x); acc[1] += w1 * bfhi(r1[p].x);
            acc[2] += w1 * bflo(r1[p].y); acc[3] += w1 * bfhi(r1[p].y);
            acc[4] += w1 * bflo(r1[p].z); acc[5] += w1 * bfhi(r1[p].z);
            acc[6] += w1 * bflo(r1[p].w); acc[7] += w1 * bfhi(r1[p].w);
        }
    }
    // merge column halves: lane l8 and l8^4 hold c0/c1 parts of the same dims
#pragma unroll
    for (int i = 0; i < 8; ++i) acc[i] += __shfl_xor(acc[i], 4);

    if (half == 0) {
        // lane l8 (0..3) owns dims 8*l8 .. 8*l8+7 of head h.
        // swizzled A-frag: row = bq, col = h*32 + 8*l8 + j -> kc=h, q2=l8, j=0..7
        const int bq = bq0 + qq;
        const int rt = bq >> 4, mm = bq & 15;
        uint4 pk;
        pk.x = (unsigned)f2bf(acc[0]) | ((unsigned)f2bf(acc[1]) << 16);
        pk.y = (unsigned)f2bf(acc[2]) | ((unsigned)f2bf(acc[3]) << 16);
        pk.z = (unsigned)f2bf(acc[4]) | ((unsigned)f2bf(acc[5]) << 16);
        pk.w = (unsigned)f2bf(acc[6]) | ((unsigned)f2bf(acc[7]) << 16);
        *(uint4*)(AccSw + (size_t)((rt * 8 + h) * 64 + (l8 * 16 + mm)) * 8) = pk;
    }
}

extern "C" void kernel_launch(void* const* d_in, const int* in_sizes, int n_in,
                              void* d_out, int out_size, void* d_ws, size_t ws_size,
                              hipStream_t stream) {
    const float* query  = (const float*)d_in[0];
    const float* refp   = (const float*)d_in[1];
    const float* inflat = (const float*)d_in[2];
    const float* Wv    = (const float*)d_in[4];
    const float* bv    = (const float*)d_in[5];
    const float* Woff  = (const float*)d_in[6];
    const float* boff  = (const float*)d_in[7];
    const float* Wattn = (const float*)d_in[8];
    const float* battn = (const float*)d_in[9];
    const float* Wout  = (const float*)d_in[10];
    const float* bout  = (const float*)d_in[11];
    float* out = (float*)d_out;

    char* p = (char*)d_ws;
    const size_t aswBytes = (size_t)MT_PAD * 8 * 64 * 8 * sizeof(unsigned short); // 13.63 MB
    unsigned short* AswV = (unsigned short*)p;           p += aswBytes;  // value A-frags / AccSw
    unsigned short* AswQ = (unsigned short*)p;           p += aswBytes;
    unsigned short* BswV = (unsigned short*)p;           p += (size_t)8 * 16 * 64 * 8 * 2;
    unsigned short* BswOA = (unsigned short*)p;          p += (size_t)8 * 24 * 64 * 8 * 2;
    unsigned short* BswO = (unsigned short*)p;           p += (size_t)8 * 16 * 64 * 8 * 2;
    float* fbias = (float*)p;                            p += 384 * sizeof(float);
    unsigned short* value = (unsigned short*)p;          p += (size_t)M_TOTAL * 256 * 2;
    float* fused = (float*)p;                            p += (size_t)M_TOTAL * 384 * 4;
    unsigned short* AccSw = AswV;   // alias: dual consumes AswV before sampler writes

    const int M = M_TOTAL;

    conv_all_kernel<<<dim3(MT_PAD * 2 + 57, 2), 256, 0, stream>>>(
        inflat, AswV, query, AswQ, Wv, Woff, Wattn, Wout, boff, battn,
        BswV, BswOA, BswO, fbias, M);
    dual_gemm_kernel<<<dim3(10, RBLK), 256, 0, stream>>>(
        (const short8*)AswV, (const short8*)AswQ,
        (const short8*)BswV, (const short8*)BswOA,
        bv, fbias, value, fused, M);
    msda_sample_kernel<<<M / 4, 256, 0, stream>>>(refp, value, fused, AccSw);
    out_gemm_kernel<<<dim3(4, RBLK), 256, 0, stream>>>(
        (const short8*)AccSw, (const short8*)BswO, bout, out, M);
}